// Round 13
// baseline (250.127 us; speedup 1.0000x reference)
//
#include <hip/hip_runtime.h>
#include <hip/hip_fp16.h>

#define NN 100000
#define NE 1600000
#define NPB 128                        // nodes per bucket
#define NBUCK ((NN + NPB - 1) / NPB)   // 782
#define CAP 5120                       // reserved slots per bucket (align-16 slack incl)
#define PBLOCKS 256
#define PTPB 512
#define EPB (NE / PBLOCKS)             // 6250
#define DUMMY 100000u                  // pad src: hws row NN is all-zero
#define SENT 0xFFFFFFFFu               // reservation-slack sentinel (memset 0xFF)
#define GBLK 4096                      // gather blocks
#define NSLOT (GBLK * 8)               // 32768 half-wave slots (2 nodes per wave)

// ---- bucket partition, 64B-aligned per-(block,bucket) runs: packed = (dst&127)<<17 | src ----
// packed[] is pre-memset to SENT; slack needs no fill pass.
__global__ __launch_bounds__(PTPB) void part_kernel(const int* __restrict__ src,
                                                    const int* __restrict__ dst,
                                                    unsigned int* __restrict__ bcount,
                                                    unsigned int* __restrict__ packed) {
    __shared__ unsigned int lcnt[NBUCK];
    __shared__ unsigned int lcur[NBUCK];
    for (int i = threadIdx.x; i < NBUCK; i += PTPB) lcnt[i] = 0u;
    __syncthreads();
    int e0 = blockIdx.x * EPB;
    for (int e = e0 + threadIdx.x; e < e0 + EPB; e += PTPB)
        atomicAdd(&lcnt[((unsigned)dst[e]) >> 7], 1u);
    __syncthreads();
    for (int i = threadIdx.x; i < NBUCK; i += PTPB) {
        unsigned int c = lcnt[i];
        unsigned int rc = (c + 15u) & ~15u;              // 64B-aligned reservation
        lcur[i] = rc ? atomicAdd(&bcount[i], rc) : 0u;   // line owned by one block
    }
    __syncthreads();
    for (int e = e0 + threadIdx.x; e < e0 + EPB; e += PTPB) {
        unsigned int d = (unsigned)dst[e];
        unsigned int b = d >> 7;
        unsigned int pos = atomicAdd(&lcur[b], 1u);
        packed[(size_t)b * CAP + pos] = ((d & 127u) << 17) | (unsigned)src[e];
    }
}

// ---- per-bucket counting sort (skip sentinels), pad node lists to mult of 8 ----
// writes rsd[node] = row_start | (padded_deg/8)<<22  and dinv[node]
__global__ __launch_bounds__(512) void sort_kernel(const unsigned int* __restrict__ bcount,
                                                   unsigned int* __restrict__ packed,
                                                   unsigned int* __restrict__ rsd,
                                                   float* __restrict__ dinv) {
    __shared__ unsigned int lraw[CAP];
    __shared__ unsigned int lsort[CAP];
    __shared__ unsigned int cnt[NPB];
    __shared__ unsigned int ps[NPB];   // inclusive prefix of PADDED counts
    __shared__ unsigned int cur[NPB];
    __shared__ unsigned int ntot;
    int b = blockIdx.x;
    int tid = threadIdx.x;
    if (tid < NPB) cnt[tid] = 0u;
    __syncthreads();
    unsigned int n = bcount[b];        // reserved total (includes sentinel holes)
    unsigned int* pk = packed + (size_t)b * CAP;
    for (unsigned int i = tid; i < n; i += 512) {
        unsigned int p = pk[i];
        lraw[i] = p;
        if (p != SENT) atomicAdd(&cnt[p >> 17], 1u);
    }
    __syncthreads();
    if (tid < NPB) ps[tid] = (cnt[tid] + 7u) & ~7u;  // padded count
    __syncthreads();
    for (int off = 1; off < NPB; off <<= 1) {
        unsigned int t = (tid < NPB && tid >= off) ? ps[tid - off] : 0u;
        __syncthreads();
        if (tid < NPB) ps[tid] += t;
        __syncthreads();
    }
    if (tid == NPB - 1) ntot = ps[NPB - 1];
    __syncthreads();
    unsigned int np = ntot;
    for (unsigned int i = tid; i < np; i += 512) lsort[i] = DUMMY;
    if (tid < NPB) cur[tid] = ps[tid] - ((cnt[tid] + 7u) & ~7u);
    __syncthreads();
    for (unsigned int i = tid; i < n; i += 512) {
        unsigned int p = lraw[i];
        if (p != SENT) {
            unsigned int pos = atomicAdd(&cur[p >> 17], 1u);
            lsort[pos] = p & 0x1FFFFu;
        }
    }
    __syncthreads();
    for (unsigned int i = tid; i < np; i += 512) pk[i] = lsort[i];
    if (tid < NPB) {
        int node = b * NPB + tid;
        if (node < NN) {
            unsigned int c = cnt[tid];
            unsigned int pc = (c + 7u) & ~7u;
            unsigned int rs = (unsigned int)(b * CAP) + ps[tid] - pc;  // < 2^22 (4.00M)
            rsd[node] = rs | ((pc >> 3) << 22);
            dinv[node] = rsqrtf((float)c + 1.0f);   // real deg + self-loop
        }
    }
}

// ---------------- embed MLP + hws1 = fp16((h @ Wg1) * dinv); zeros pad row NN ----------------
__global__ __launch_bounds__(256) void embed_kernel(
    const float* __restrict__ x, const float* __restrict__ We1, const float* __restrict__ be1,
    const float* __restrict__ We2, const float* __restrict__ be2, const float* __restrict__ Wg1,
    const float* __restrict__ dinv, __half* __restrict__ hws1, __half* __restrict__ hws2) {
    __shared__ float sWe1[6 * 64];
    __shared__ float sbe1[64];
    __shared__ float sWe2[64 * 32];
    __shared__ float sbe2[32];
    __shared__ float sWg1[32 * 32];
    for (int i = threadIdx.x; i < 6 * 64; i += 256) sWe1[i] = We1[i];
    for (int i = threadIdx.x; i < 64; i += 256) sbe1[i] = be1[i];
    for (int i = threadIdx.x; i < 64 * 32; i += 256) sWe2[i] = We2[i];
    for (int i = threadIdx.x; i < 32; i += 256) sbe2[i] = be2[i];
    for (int i = threadIdx.x; i < 32 * 32; i += 256) sWg1[i] = Wg1[i];
    __syncthreads();

    int node = blockIdx.x * 256 + threadIdx.x;
    if (node > NN) return;
    if (node == NN) {  // zero pad rows for DUMMY src
        for (int j = 0; j < 32; j++) {
            hws1[(size_t)NN * 32 + j] = __float2half(0.f);
            hws2[(size_t)NN * 32 + j] = __float2half(0.f);
        }
        return;
    }

    float xv[6];
#pragma unroll
    for (int k = 0; k < 6; k++) xv[k] = x[node * 6 + k];

    float h1[64];
#pragma unroll
    for (int j = 0; j < 64; j++) {
        float a = sbe1[j];
#pragma unroll
        for (int k = 0; k < 6; k++) a += xv[k] * sWe1[k * 64 + j];
        h1[j] = tanhf(a);
    }

    float h[32];
#pragma unroll 4
    for (int j = 0; j < 32; j++) {
        float a = sbe2[j];
#pragma unroll
        for (int k = 0; k < 64; k++) a += h1[k] * sWe2[k * 32 + j];
        h[j] = tanhf(a);
    }

    float di = dinv[node];
    __half* o = hws1 + (size_t)node * 32;
#pragma unroll 4
    for (int j = 0; j < 32; j++) {
        float a = 0.f;
#pragma unroll
        for (int k = 0; k < 32; k++) a += h[k] * sWg1[k * 32 + j];
        o[j] = __float2half(a * di);
    }
}

// ---- gather1: 2 nodes per wave (32 lanes each), W in VGPRs, rsd prefetch ----
__global__ __launch_bounds__(256) void gather1_kernel(
    const unsigned int* __restrict__ sorted, const unsigned int* __restrict__ rsd,
    const float* __restrict__ dinv, const __half* __restrict__ hws1,
    const float* __restrict__ bg1, const float* __restrict__ Wg2,
    __half* __restrict__ hws2) {
    int lane = threadIdx.x & 31;  // lane within half-wave
    int g = lane >> 4;            // edge group 0..1
    int p = lane & 15;            // feature pair
    int f = lane;                 // feature (epilogue)
    float wreg[32];
#pragma unroll
    for (int k = 0; k < 32; k++) wreg[k] = Wg2[k * 32 + f];  // column f in regs
    float bf = bg1[f];
    int slot = (blockIdx.x * 256 + threadIdx.x) >> 5;  // half-wave id
    const __half2* H = (const __half2*)hws1;
    int node = slot;
    if (node >= NN) return;
    unsigned int r = rsd[node];
    while (node < NN) {
        int nxt = node + NSLOT;
        unsigned int rn = (nxt < NN) ? rsd[nxt] : 0u;  // prefetch next descriptor
        unsigned int base = r & 0x3FFFFFu;
        unsigned int d = (r >> 22) << 3;
        float ax = 0.f, ay = 0.f;
        for (unsigned int k = g * 4; k < d; k += 8) {  // 8 rows/node in flight
            uint4 s4 = *reinterpret_cast<const uint4*>(sorted + base + k);
            float2 v0 = __half22float2(H[(size_t)s4.x * 16 + p]);
            float2 v1 = __half22float2(H[(size_t)s4.y * 16 + p]);
            float2 v2 = __half22float2(H[(size_t)s4.z * 16 + p]);
            float2 v3 = __half22float2(H[(size_t)s4.w * 16 + p]);
            ax += (v0.x + v1.x) + (v2.x + v3.x);
            ay += (v0.y + v1.y) + (v2.y + v3.y);
        }
        ax += __shfl_xor(ax, 16); ay += __shfl_xor(ay, 16);  // combine 2 groups
        float2 sv = __half22float2(H[(size_t)node * 16 + p]);  // self-loop
        ax += sv.x; ay += sv.y;
        float ae = __shfl(ax, f >> 1, 32);
        float ao = __shfl(ay, f >> 1, 32);
        float av = (f & 1) ? ao : ae;
        float di = dinv[node];
        float h = di * av + bf;
        h = h > 0.f ? h : 0.f;
        float o = 0.f;
#pragma unroll
        for (int k = 0; k < 32; k++) o += __shfl(h, k, 32) * wreg[k];
        hws2[(size_t)node * 32 + f] = __float2half(o * di);
        node = nxt; r = rn;
    }
}

// ---- gather2: 2 nodes per wave, conv2 + prediction MLP, rsd prefetch ----
__global__ __launch_bounds__(256) void gather2_kernel(
    const unsigned int* __restrict__ sorted, const unsigned int* __restrict__ rsd,
    const float* __restrict__ dinv, const __half* __restrict__ hws2,
    const float* __restrict__ bg2, const float* __restrict__ Wp1,
    const float* __restrict__ bp1, const float* __restrict__ Wp2,
    const float* __restrict__ bp2, float* __restrict__ out) {
    int lane = threadIdx.x & 31;
    int g = lane >> 4;
    int p = lane & 15;
    int f = lane;
    float wreg[32];
#pragma unroll
    for (int k = 0; k < 32; k++) wreg[k] = Wp1[k * 32 + f];
    float bgf = bg2[f];
    float b1f = bp1[f];
    float w2f = Wp2[f];
    float b2 = bp2[0];
    int slot = (blockIdx.x * 256 + threadIdx.x) >> 5;
    const __half2* H = (const __half2*)hws2;
    int node = slot;
    if (node >= NN) return;
    unsigned int r = rsd[node];
    while (node < NN) {
        int nxt = node + NSLOT;
        unsigned int rn = (nxt < NN) ? rsd[nxt] : 0u;
        unsigned int base = r & 0x3FFFFFu;
        unsigned int d = (r >> 22) << 3;
        float ax = 0.f, ay = 0.f;
        for (unsigned int k = g * 4; k < d; k += 8) {
            uint4 s4 = *reinterpret_cast<const uint4*>(sorted + base + k);
            float2 v0 = __half22float2(H[(size_t)s4.x * 16 + p]);
            float2 v1 = __half22float2(H[(size_t)s4.y * 16 + p]);
            float2 v2 = __half22float2(H[(size_t)s4.z * 16 + p]);
            float2 v3 = __half22float2(H[(size_t)s4.w * 16 + p]);
            ax += (v0.x + v1.x) + (v2.x + v3.x);
            ay += (v0.y + v1.y) + (v2.y + v3.y);
        }
        ax += __shfl_xor(ax, 16); ay += __shfl_xor(ay, 16);
        float2 sv = __half22float2(H[(size_t)node * 16 + p]);
        ax += sv.x; ay += sv.y;
        float ae = __shfl(ax, f >> 1, 32);
        float ao = __shfl(ay, f >> 1, 32);
        float av = (f & 1) ? ao : ae;
        float di = dinv[node];
        float h = di * av + bgf;
        h = h > 0.f ? h : 0.f;
        float pre = b1f;
#pragma unroll
        for (int k = 0; k < 32; k++) pre += __shfl(h, k, 32) * wreg[k];
        float t = tanhf(pre) * w2f;
#pragma unroll
        for (int off = 1; off < 32; off <<= 1) t += __shfl_xor(t, off);
        if (lane == 0) out[node] = tanhf(t + b2);
        node = nxt; r = rn;
    }
}

extern "C" void kernel_launch(void* const* d_in, const int* in_sizes, int n_in,
                              void* d_out, int out_size, void* d_ws, size_t ws_size,
                              hipStream_t stream) {
    const float* x = (const float*)d_in[0];
    const int* edge = (const int*)d_in[1];  // [2, NE] int32
    const int* src = edge;
    const int* dst = edge + NE;
    const float* We1 = (const float*)d_in[2];
    const float* be1 = (const float*)d_in[3];
    const float* We2 = (const float*)d_in[4];
    const float* be2 = (const float*)d_in[5];
    const float* Wg1 = (const float*)d_in[6];
    const float* bg1 = (const float*)d_in[7];
    const float* Wg2 = (const float*)d_in[8];
    const float* bg2 = (const float*)d_in[9];
    const float* Wp1 = (const float*)d_in[10];
    const float* bp1 = (const float*)d_in[11];
    const float* Wp2 = (const float*)d_in[12];
    const float* bp2 = (const float*)d_in[13];
    float* out = (float*)d_out;

    // workspace (4B units):
    // bcount[1024] | dinv[NN] | rsd[NN] | packed[NBUCK*CAP] | hws1 | hws2
    unsigned int* bcount = (unsigned int*)d_ws;
    float* dinv = (float*)d_ws + 1024;
    unsigned int* rsd = (unsigned int*)d_ws + 1024 + NN;
    unsigned int* packed = (unsigned int*)d_ws + 1024 + 2 * NN;
    __half* hws1 = (__half*)((unsigned int*)d_ws + 1024 + 2 * NN + NBUCK * CAP);
    __half* hws2 = hws1 + (size_t)(NN + 1) * 32;

    hipMemsetAsync(bcount, 0, 1024 * sizeof(unsigned int), stream);
    hipMemsetAsync(packed, 0xFF, (size_t)NBUCK * CAP * 4, stream);  // pre-fill SENT

    int gridN = (NN + 256) / 256;       // covers node NN (pad-row writer)

    part_kernel<<<PBLOCKS, PTPB, 0, stream>>>(src, dst, bcount, packed);
    sort_kernel<<<NBUCK, 512, 0, stream>>>(bcount, packed, rsd, dinv);
    embed_kernel<<<gridN, 256, 0, stream>>>(x, We1, be1, We2, be2, Wg1, dinv, hws1, hws2);
    gather1_kernel<<<GBLK, 256, 0, stream>>>(packed, rsd, dinv, hws1, bg1, Wg2, hws2);
    gather2_kernel<<<GBLK, 256, 0, stream>>>(packed, rsd, dinv, hws2, bg2, Wp1, bp1, Wp2, bp2, out);
}

// Round 14
// 245.937 us; speedup vs baseline: 1.0170x; 1.0170x over previous
//
#include <hip/hip_runtime.h>
#include <hip/hip_fp16.h>

#define NN 100000
#define NE 1600000
#define NPB 128                        // nodes per bucket
#define NBUCK ((NN + NPB - 1) / NPB)   // 782
#define CAP 4608                       // reserved slots per bucket (align-16 slack incl)
#define PBLOCKS 128
#define PTPB 1024
#define EPB (NE / PBLOCKS)             // 12500
#define DUMMY 100000u                  // pad src: hws row NN is all-zero
#define SENT 0xFFFFFFFFu               // reservation-slack sentinel (memset 0xFF)
#define GBLK 4096                      // gather blocks
#define NSLOT (GBLK * 8)               // 32768 half-wave slots (2 nodes per wave-half pair)

// ---- bucket partition, 64B-aligned per-(block,bucket) runs: packed = (dst&127)<<17 | src ----
// packed[] is pre-memset to SENT; slack needs no fill pass.
__global__ __launch_bounds__(PTPB) void part_kernel(const int* __restrict__ src,
                                                    const int* __restrict__ dst,
                                                    unsigned int* __restrict__ bcount,
                                                    unsigned int* __restrict__ packed) {
    __shared__ unsigned int lcnt[NBUCK];
    __shared__ unsigned int lcur[NBUCK];
    for (int i = threadIdx.x; i < NBUCK; i += PTPB) lcnt[i] = 0u;
    __syncthreads();
    int e0 = blockIdx.x * EPB;
    for (int e = e0 + threadIdx.x; e < e0 + EPB; e += PTPB)
        atomicAdd(&lcnt[((unsigned)dst[e]) >> 7], 1u);
    __syncthreads();
    for (int i = threadIdx.x; i < NBUCK; i += PTPB) {
        unsigned int c = lcnt[i];
        unsigned int rc = (c + 15u) & ~15u;              // 64B-aligned reservation
        lcur[i] = rc ? atomicAdd(&bcount[i], rc) : 0u;   // line owned by one block
    }
    __syncthreads();
    for (int e = e0 + threadIdx.x; e < e0 + EPB; e += PTPB) {
        unsigned int d = (unsigned)dst[e];
        unsigned int b = d >> 7;
        unsigned int pos = atomicAdd(&lcur[b], 1u);
        packed[(size_t)b * CAP + pos] = ((d & 127u) << 17) | (unsigned)src[e];
    }
}

// ---- per-bucket counting sort (skip sentinels), pad node lists to mult of 8 ----
// writes rsd[node] = row_start | (padded_deg/8)<<22  and dinv[node]
__global__ __launch_bounds__(512) void sort_kernel(const unsigned int* __restrict__ bcount,
                                                   unsigned int* __restrict__ packed,
                                                   unsigned int* __restrict__ rsd,
                                                   float* __restrict__ dinv) {
    __shared__ unsigned int lraw[CAP];
    __shared__ unsigned int lsort[CAP];
    __shared__ unsigned int cnt[NPB];
    __shared__ unsigned int ps[NPB];   // inclusive prefix of PADDED counts
    __shared__ unsigned int cur[NPB];
    __shared__ unsigned int ntot;
    int b = blockIdx.x;
    int tid = threadIdx.x;
    if (tid < NPB) cnt[tid] = 0u;
    __syncthreads();
    unsigned int n = bcount[b];        // reserved total (includes sentinel holes)
    unsigned int* pk = packed + (size_t)b * CAP;
    for (unsigned int i = tid; i < n; i += 512) {
        unsigned int p = pk[i];
        lraw[i] = p;
        if (p != SENT) atomicAdd(&cnt[p >> 17], 1u);
    }
    __syncthreads();
    if (tid < NPB) ps[tid] = (cnt[tid] + 7u) & ~7u;  // padded count
    __syncthreads();
    for (int off = 1; off < NPB; off <<= 1) {
        unsigned int t = (tid < NPB && tid >= off) ? ps[tid - off] : 0u;
        __syncthreads();
        if (tid < NPB) ps[tid] += t;
        __syncthreads();
    }
    if (tid == NPB - 1) ntot = ps[NPB - 1];
    __syncthreads();
    unsigned int np = ntot;
    for (unsigned int i = tid; i < np; i += 512) lsort[i] = DUMMY;
    if (tid < NPB) cur[tid] = ps[tid] - ((cnt[tid] + 7u) & ~7u);
    __syncthreads();
    for (unsigned int i = tid; i < n; i += 512) {
        unsigned int p = lraw[i];
        if (p != SENT) {
            unsigned int pos = atomicAdd(&cur[p >> 17], 1u);
            lsort[pos] = p & 0x1FFFFu;
        }
    }
    __syncthreads();
    for (unsigned int i = tid; i < np; i += 512) pk[i] = lsort[i];
    if (tid < NPB) {
        int node = b * NPB + tid;
        if (node < NN) {
            unsigned int c = cnt[tid];
            unsigned int pc = (c + 7u) & ~7u;
            unsigned int rs = (unsigned int)(b * CAP) + ps[tid] - pc;  // < 2^22 (3.6M)
            rsd[node] = rs | ((pc >> 3) << 22);
            dinv[node] = rsqrtf((float)c + 1.0f);   // real deg + self-loop
        }
    }
}

// ---------------- embed MLP + hws1 = fp16((h @ Wg1) * dinv); zeros pad row NN ----------------
__global__ __launch_bounds__(256) void embed_kernel(
    const float* __restrict__ x, const float* __restrict__ We1, const float* __restrict__ be1,
    const float* __restrict__ We2, const float* __restrict__ be2, const float* __restrict__ Wg1,
    const float* __restrict__ dinv, __half* __restrict__ hws1, __half* __restrict__ hws2) {
    __shared__ float sWe1[6 * 64];
    __shared__ float sbe1[64];
    __shared__ float sWe2[64 * 32];
    __shared__ float sbe2[32];
    __shared__ float sWg1[32 * 32];
    for (int i = threadIdx.x; i < 6 * 64; i += 256) sWe1[i] = We1[i];
    for (int i = threadIdx.x; i < 64; i += 256) sbe1[i] = be1[i];
    for (int i = threadIdx.x; i < 64 * 32; i += 256) sWe2[i] = We2[i];
    for (int i = threadIdx.x; i < 32; i += 256) sbe2[i] = be2[i];
    for (int i = threadIdx.x; i < 32 * 32; i += 256) sWg1[i] = Wg1[i];
    __syncthreads();

    int node = blockIdx.x * 256 + threadIdx.x;
    if (node > NN) return;
    if (node == NN) {  // zero pad rows for DUMMY src
        for (int j = 0; j < 32; j++) {
            hws1[(size_t)NN * 32 + j] = __float2half(0.f);
            hws2[(size_t)NN * 32 + j] = __float2half(0.f);
        }
        return;
    }

    float xv[6];
#pragma unroll
    for (int k = 0; k < 6; k++) xv[k] = x[node * 6 + k];

    float h1[64];
#pragma unroll
    for (int j = 0; j < 64; j++) {
        float a = sbe1[j];
#pragma unroll
        for (int k = 0; k < 6; k++) a += xv[k] * sWe1[k * 64 + j];
        h1[j] = tanhf(a);
    }

    float h[32];
#pragma unroll 4
    for (int j = 0; j < 32; j++) {
        float a = sbe2[j];
#pragma unroll
        for (int k = 0; k < 64; k++) a += h1[k] * sWe2[k * 32 + j];
        h[j] = tanhf(a);
    }

    float di = dinv[node];
    __half* o = hws1 + (size_t)node * 32;
#pragma unroll 4
    for (int j = 0; j < 32; j++) {
        float a = 0.f;
#pragma unroll
        for (int k = 0; k < 32; k++) a += h[k] * sWg1[k * 32 + j];
        o[j] = __float2half(a * di);
    }
}

// ---- gather1: dual-node per half-wave (interleaved edge loops), W in VGPRs ----
__global__ __launch_bounds__(256) void gather1_kernel(
    const unsigned int* __restrict__ sorted, const unsigned int* __restrict__ rsd,
    const float* __restrict__ dinv, const __half* __restrict__ hws1,
    const float* __restrict__ bg1, const float* __restrict__ Wg2,
    __half* __restrict__ hws2) {
    int lane = threadIdx.x & 31;  // lane within half-wave
    int g = lane >> 4;            // edge group 0..1
    int p = lane & 15;            // feature pair
    int f = lane;                 // feature (epilogue)
    float wreg[32];
#pragma unroll
    for (int k = 0; k < 32; k++) wreg[k] = Wg2[k * 32 + f];  // column f in regs
    float bf = bg1[f];
    int slot = (blockIdx.x * 256 + threadIdx.x) >> 5;  // half-wave id, 0..NSLOT-1
    const __half2* H = (const __half2*)hws1;
    for (int na = slot; na < NN; na += 2 * NSLOT) {
        int nb = na + NSLOT;
        bool hb = nb < NN;
        unsigned int ra = rsd[na];
        unsigned int rb = hb ? rsd[nb] : 0u;
        unsigned int base_a = ra & 0x3FFFFFu, da = (ra >> 22) << 3;
        unsigned int base_b = rb & 0x3FFFFFu, db = hb ? ((rb >> 22) << 3) : 0u;
        float ax = 0.f, ay = 0.f, bx2 = 0.f, by2 = 0.f;
        unsigned int dmin = da < db ? da : db;
        unsigned int k = g * 4;
        for (; k < dmin; k += 8) {  // interleaved: 2 uint4 + 8 rows in flight
            uint4 sa = *reinterpret_cast<const uint4*>(sorted + base_a + k);
            uint4 sb = *reinterpret_cast<const uint4*>(sorted + base_b + k);
            float2 a0 = __half22float2(H[(size_t)sa.x * 16 + p]);
            float2 a1 = __half22float2(H[(size_t)sa.y * 16 + p]);
            float2 a2 = __half22float2(H[(size_t)sa.z * 16 + p]);
            float2 a3 = __half22float2(H[(size_t)sa.w * 16 + p]);
            float2 b0 = __half22float2(H[(size_t)sb.x * 16 + p]);
            float2 b1 = __half22float2(H[(size_t)sb.y * 16 + p]);
            float2 b2 = __half22float2(H[(size_t)sb.z * 16 + p]);
            float2 b3 = __half22float2(H[(size_t)sb.w * 16 + p]);
            ax += (a0.x + a1.x) + (a2.x + a3.x);
            ay += (a0.y + a1.y) + (a2.y + a3.y);
            bx2 += (b0.x + b1.x) + (b2.x + b3.x);
            by2 += (b0.y + b1.y) + (b2.y + b3.y);
        }
        for (unsigned int ka = k; ka < da; ka += 8) {
            uint4 sa = *reinterpret_cast<const uint4*>(sorted + base_a + ka);
            float2 a0 = __half22float2(H[(size_t)sa.x * 16 + p]);
            float2 a1 = __half22float2(H[(size_t)sa.y * 16 + p]);
            float2 a2 = __half22float2(H[(size_t)sa.z * 16 + p]);
            float2 a3 = __half22float2(H[(size_t)sa.w * 16 + p]);
            ax += (a0.x + a1.x) + (a2.x + a3.x);
            ay += (a0.y + a1.y) + (a2.y + a3.y);
        }
        for (unsigned int kb = k; kb < db; kb += 8) {
            uint4 sb = *reinterpret_cast<const uint4*>(sorted + base_b + kb);
            float2 b0 = __half22float2(H[(size_t)sb.x * 16 + p]);
            float2 b1 = __half22float2(H[(size_t)sb.y * 16 + p]);
            float2 b2 = __half22float2(H[(size_t)sb.z * 16 + p]);
            float2 b3 = __half22float2(H[(size_t)sb.w * 16 + p]);
            bx2 += (b0.x + b1.x) + (b2.x + b3.x);
            by2 += (b0.y + b1.y) + (b2.y + b3.y);
        }
        // epilogue A
        ax += __shfl_xor(ax, 16); ay += __shfl_xor(ay, 16);
        float2 sv = __half22float2(H[(size_t)na * 16 + p]);
        ax += sv.x; ay += sv.y;
        float ae = __shfl(ax, f >> 1, 32);
        float ao = __shfl(ay, f >> 1, 32);
        float av = (f & 1) ? ao : ae;
        float dia = dinv[na];
        float ha = dia * av + bf;
        ha = ha > 0.f ? ha : 0.f;
        float oa = 0.f;
#pragma unroll
        for (int k2 = 0; k2 < 32; k2++) oa += __shfl(ha, k2, 32) * wreg[k2];
        hws2[(size_t)na * 32 + f] = __float2half(oa * dia);
        // epilogue B
        if (hb) {
            bx2 += __shfl_xor(bx2, 16); by2 += __shfl_xor(by2, 16);
            float2 svb = __half22float2(H[(size_t)nb * 16 + p]);
            bx2 += svb.x; by2 += svb.y;
            float be = __shfl(bx2, f >> 1, 32);
            float bo = __shfl(by2, f >> 1, 32);
            float bv = (f & 1) ? bo : be;
            float dib = dinv[nb];
            float hbv = dib * bv + bf;
            hbv = hbv > 0.f ? hbv : 0.f;
            float ob = 0.f;
#pragma unroll
            for (int k2 = 0; k2 < 32; k2++) ob += __shfl(hbv, k2, 32) * wreg[k2];
            hws2[(size_t)nb * 32 + f] = __float2half(ob * dib);
        }
    }
}

// ---- gather2: dual-node per half-wave, conv2 + prediction MLP ----
__global__ __launch_bounds__(256) void gather2_kernel(
    const unsigned int* __restrict__ sorted, const unsigned int* __restrict__ rsd,
    const float* __restrict__ dinv, const __half* __restrict__ hws2,
    const float* __restrict__ bg2, const float* __restrict__ Wp1,
    const float* __restrict__ bp1, const float* __restrict__ Wp2,
    const float* __restrict__ bp2, float* __restrict__ out) {
    int lane = threadIdx.x & 31;
    int g = lane >> 4;
    int p = lane & 15;
    int f = lane;
    float wreg[32];
#pragma unroll
    for (int k = 0; k < 32; k++) wreg[k] = Wp1[k * 32 + f];
    float bgf = bg2[f];
    float b1f = bp1[f];
    float w2f = Wp2[f];
    float b2 = bp2[0];
    int slot = (blockIdx.x * 256 + threadIdx.x) >> 5;
    const __half2* H = (const __half2*)hws2;
    for (int na = slot; na < NN; na += 2 * NSLOT) {
        int nb = na + NSLOT;
        bool hb = nb < NN;
        unsigned int ra = rsd[na];
        unsigned int rb = hb ? rsd[nb] : 0u;
        unsigned int base_a = ra & 0x3FFFFFu, da = (ra >> 22) << 3;
        unsigned int base_b = rb & 0x3FFFFFu, db = hb ? ((rb >> 22) << 3) : 0u;
        float ax = 0.f, ay = 0.f, bx2 = 0.f, by2 = 0.f;
        unsigned int dmin = da < db ? da : db;
        unsigned int k = g * 4;
        for (; k < dmin; k += 8) {
            uint4 sa = *reinterpret_cast<const uint4*>(sorted + base_a + k);
            uint4 sb = *reinterpret_cast<const uint4*>(sorted + base_b + k);
            float2 a0 = __half22float2(H[(size_t)sa.x * 16 + p]);
            float2 a1 = __half22float2(H[(size_t)sa.y * 16 + p]);
            float2 a2 = __half22float2(H[(size_t)sa.z * 16 + p]);
            float2 a3 = __half22float2(H[(size_t)sa.w * 16 + p]);
            float2 b0 = __half22float2(H[(size_t)sb.x * 16 + p]);
            float2 b1 = __half22float2(H[(size_t)sb.y * 16 + p]);
            float2 b2 = __half22float2(H[(size_t)sb.z * 16 + p]);
            float2 b3 = __half22float2(H[(size_t)sb.w * 16 + p]);
            ax += (a0.x + a1.x) + (a2.x + a3.x);
            ay += (a0.y + a1.y) + (a2.y + a3.y);
            bx2 += (b0.x + b1.x) + (b2.x + b3.x);
            by2 += (b0.y + b1.y) + (b2.y + b3.y);
        }
        for (unsigned int ka = k; ka < da; ka += 8) {
            uint4 sa = *reinterpret_cast<const uint4*>(sorted + base_a + ka);
            float2 a0 = __half22float2(H[(size_t)sa.x * 16 + p]);
            float2 a1 = __half22float2(H[(size_t)sa.y * 16 + p]);
            float2 a2 = __half22float2(H[(size_t)sa.z * 16 + p]);
            float2 a3 = __half22float2(H[(size_t)sa.w * 16 + p]);
            ax += (a0.x + a1.x) + (a2.x + a3.x);
            ay += (a0.y + a1.y) + (a2.y + a3.y);
        }
        for (unsigned int kb = k; kb < db; kb += 8) {
            uint4 sb = *reinterpret_cast<const uint4*>(sorted + base_b + kb);
            float2 b0 = __half22float2(H[(size_t)sb.x * 16 + p]);
            float2 b1 = __half22float2(H[(size_t)sb.y * 16 + p]);
            float2 b2 = __half22float2(H[(size_t)sb.z * 16 + p]);
            float2 b3 = __half22float2(H[(size_t)sb.w * 16 + p]);
            bx2 += (b0.x + b1.x) + (b2.x + b3.x);
            by2 += (b0.y + b1.y) + (b2.y + b3.y);
        }
        // epilogue A
        ax += __shfl_xor(ax, 16); ay += __shfl_xor(ay, 16);
        float2 sv = __half22float2(H[(size_t)na * 16 + p]);
        ax += sv.x; ay += sv.y;
        float ae = __shfl(ax, f >> 1, 32);
        float ao = __shfl(ay, f >> 1, 32);
        float av = (f & 1) ? ao : ae;
        float dia = dinv[na];
        float ha = dia * av + bgf;
        ha = ha > 0.f ? ha : 0.f;
        float pre = b1f;
#pragma unroll
        for (int k2 = 0; k2 < 32; k2++) pre += __shfl(ha, k2, 32) * wreg[k2];
        float t = tanhf(pre) * w2f;
#pragma unroll
        for (int off = 1; off < 32; off <<= 1) t += __shfl_xor(t, off);
        if (lane == 0) out[na] = tanhf(t + b2);
        // epilogue B
        if (hb) {
            bx2 += __shfl_xor(bx2, 16); by2 += __shfl_xor(by2, 16);
            float2 svb = __half22float2(H[(size_t)nb * 16 + p]);
            bx2 += svb.x; by2 += svb.y;
            float be = __shfl(bx2, f >> 1, 32);
            float bo = __shfl(by2, f >> 1, 32);
            float bv = (f & 1) ? bo : be;
            float dib = dinv[nb];
            float hbv = dib * bv + bgf;
            hbv = hbv > 0.f ? hbv : 0.f;
            float preb = b1f;
#pragma unroll
            for (int k2 = 0; k2 < 32; k2++) preb += __shfl(hbv, k2, 32) * wreg[k2];
            float tb = tanhf(preb) * w2f;
#pragma unroll
            for (int off = 1; off < 32; off <<= 1) tb += __shfl_xor(tb, off);
            if (lane == 0) out[nb] = tanhf(tb + b2);
        }
    }
}

extern "C" void kernel_launch(void* const* d_in, const int* in_sizes, int n_in,
                              void* d_out, int out_size, void* d_ws, size_t ws_size,
                              hipStream_t stream) {
    const float* x = (const float*)d_in[0];
    const int* edge = (const int*)d_in[1];  // [2, NE] int32
    const int* src = edge;
    const int* dst = edge + NE;
    const float* We1 = (const float*)d_in[2];
    const float* be1 = (const float*)d_in[3];
    const float* We2 = (const float*)d_in[4];
    const float* be2 = (const float*)d_in[5];
    const float* Wg1 = (const float*)d_in[6];
    const float* bg1 = (const float*)d_in[7];
    const float* Wg2 = (const float*)d_in[8];
    const float* bg2 = (const float*)d_in[9];
    const float* Wp1 = (const float*)d_in[10];
    const float* bp1 = (const float*)d_in[11];
    const float* Wp2 = (const float*)d_in[12];
    const float* bp2 = (const float*)d_in[13];
    float* out = (float*)d_out;

    // workspace (4B units):
    // bcount[1024] | dinv[NN] | rsd[NN] | packed[NBUCK*CAP] | hws1 | hws2
    unsigned int* bcount = (unsigned int*)d_ws;
    float* dinv = (float*)d_ws + 1024;
    unsigned int* rsd = (unsigned int*)d_ws + 1024 + NN;
    unsigned int* packed = (unsigned int*)d_ws + 1024 + 2 * NN;
    __half* hws1 = (__half*)((unsigned int*)d_ws + 1024 + 2 * NN + NBUCK * CAP);
    __half* hws2 = hws1 + (size_t)(NN + 1) * 32;

    hipMemsetAsync(bcount, 0, 1024 * sizeof(unsigned int), stream);
    hipMemsetAsync(packed, 0xFF, (size_t)NBUCK * CAP * 4, stream);  // pre-fill SENT

    int gridN = (NN + 256) / 256;       // covers node NN (pad-row writer)

    part_kernel<<<PBLOCKS, PTPB, 0, stream>>>(src, dst, bcount, packed);
    sort_kernel<<<NBUCK, 512, 0, stream>>>(bcount, packed, rsd, dinv);
    embed_kernel<<<gridN, 256, 0, stream>>>(x, We1, be1, We2, be2, Wg1, dinv, hws1, hws2);
    gather1_kernel<<<GBLK, 256, 0, stream>>>(packed, rsd, dinv, hws1, bg1, Wg2, hws2);
    gather2_kernel<<<GBLK, 256, 0, stream>>>(packed, rsd, dinv, hws2, bg2, Wp1, bp1, Wp2, bp2, out);
}